// Round 6
// baseline (307.806 us; speedup 1.0000x reference)
//
#include <hip/hip_runtime.h>

#define DF 64
#define ELLK 32     // per-node ELL width; ovf list handles deg>32 exactly
#define WIN 64      // nodes per gather_update block (= 4 MFMA tiles)
#define CSTR 72     // csB LDS row stride in bf16 (64+8 pad de-banks stride-128)

typedef __attribute__((ext_vector_type(8))) short bf16x8;  // MFMA A/B frag
typedef __attribute__((ext_vector_type(4))) float f32x4;   // MFMA C/D frag

__device__ __forceinline__ unsigned short bf16rne(float f) {
    unsigned u = __float_as_uint(f);
    unsigned r = u + 0x7fffu + ((u >> 16) & 1u);
    return (unsigned short)(r >> 16);
}
__device__ __forceinline__ float b2f(unsigned short u) {
    return __uint_as_float((unsigned)u << 16);
}

// ---------------------------------------------------------------------------
// K1 (fused conv + edge scatter):
//  a) h (fp32) -> hbs row-major bf16 [(N+1)][64]; row N = ZERO sentinel.
//  b) scatter edges directly into a global ELL [N][32] (PERMUTED cols:
//     p(slot)=(slot&7)*4|(slot>>3) so the gather reads int4 per 8-lane
//     group) via distributed atomics on cnt[dst] (true degree; ~16 avg
//     hits/address -> low contention). Slot>=32 -> exact ovf list.
//  cnt must be pre-zeroed (hipMemsetAsync covers cnt[N]+ovfcnt).
// ---------------------------------------------------------------------------
__global__ __launch_bounds__(512) void conv_scatter(
    const float* __restrict__ h, const int* __restrict__ src,
    const int* __restrict__ dst, unsigned short* __restrict__ hbs,
    int* __restrict__ cnt, int* __restrict__ ell,
    int* __restrict__ ovf, int* __restrict__ ovfcnt, int ovfcap, int N, int E)
{
    int tid = blockIdx.x * 512 + threadIdx.x;

    // ---- conv: 8 threads per row, 16 B each ----
    if (tid < (N + 1) * 8) {
        int n = tid >> 3, f8 = tid & 7;
        unsigned short* op = &hbs[(size_t)n * DF + f8 * 8];
        if (n == N) {
            ushort4 z = {0, 0, 0, 0};
            *(ushort4*)op = z; *(ushort4*)(op + 4) = z;
        } else {
            const float* hp = &h[(size_t)n * DF + f8 * 8];
            float4 v0 = *(const float4*)hp;
            float4 v1 = *(const float4*)(hp + 4);
            ushort4 o0, o1;
            o0.x = bf16rne(v0.x); o0.y = bf16rne(v0.y); o0.z = bf16rne(v0.z); o0.w = bf16rne(v0.w);
            o1.x = bf16rne(v1.x); o1.y = bf16rne(v1.y); o1.z = bf16rne(v1.z); o1.w = bf16rne(v1.w);
            *(ushort4*)op = o0;
            *(ushort4*)(op + 4) = o1;
        }
    }

    // ---- edge scatter (grid-stride) ----
    int stride = gridDim.x * 512;
    for (int e = tid; e < E; e += stride) {
        int d = dst[e], s = src[e];
        int slot = atomicAdd(&cnt[d], 1);
        if (slot < ELLK) {
            ell[(size_t)d * ELLK + (((slot & 7) << 2) | (slot >> 3))] = s;
        } else {
            int p = atomicAdd(ovfcnt, 1);
            if (p < ovfcap) { ovf[2 * p] = d; ovf[2 * p + 1] = s; }
        }
    }
}

// ---------------------------------------------------------------------------
// K2 (fused gather + MFMA update). Block = 64-node window, 256 threads.
// Phase A (gather, wave = node): 64 lanes = 8 neighbors x 8 feat-chunks;
//   int4 ELL read (permuted cols, same-addr broadcast per 8-lane group),
//   up to 4 full-row 128 B hbs gathers (invalid slots clamp to zero row N;
//   quads 2-3 skipped by WAVE-UNIFORM branches), register accumulation +
//   3 shfl_xor, bf16 row -> LDS csB (stride-72 de-banked).
// Phase B (update, wave = 16-node tile): K4 verbatim; a2/a3 A-frags read
//   from csB instead of a global csum. dtot = cnt[] (true degree); ovf
//   features added inline. csum never touches global memory.
// ---------------------------------------------------------------------------
__global__ __launch_bounds__(256, 4) void gather_update(
    const unsigned short* __restrict__ hbs, const int* __restrict__ cnt,
    const int* __restrict__ ell, const float* __restrict__ h,
    const float* __restrict__ W, const float* __restrict__ b,
    const int* __restrict__ ovf, const int* __restrict__ ovfcnt,
    int ovfcap, float* __restrict__ out, int N)
{
    __shared__ unsigned short csB[WIN * CSTR];   // 9.2 KB
    const int t = threadIdx.x, lane = t & 63, wv = t >> 6;
    const int base = blockIdx.x * WIN;

    // ---- phase A: gather ----
    const int ew = lane >> 3;   // neighbor slot within quad (0..7)
    const int f8 = lane & 7;    // 16 B feat chunk of the 128 B row
    for (int i = 0; i < WIN / 4; ++i) {
        int ld = wv + 4 * i;
        int n = base + ld;
        if (n < N) {
            int cv = cnt[n];
            int m = cv < ELLK ? cv : ELLK;
            int ms = __builtin_amdgcn_readfirstlane(m);  // wave-uniform
            int4 pv = *(const int4*)&ell[(size_t)n * ELLK + 4 * ew];

            int i0 = (ew     < m) ? pv.x : N;
            int i1 = (ew + 8 < m) ? pv.y : N;
            bf16x8 v0 = *(const bf16x8*)&hbs[(size_t)i0 * DF + f8 * 8];
            bf16x8 v1 = *(const bf16x8*)&hbs[(size_t)i1 * DF + f8 * 8];
            bf16x8 v2 = {0,0,0,0,0,0,0,0};
            bf16x8 v3 = {0,0,0,0,0,0,0,0};
            if (ms > 16) {   // skipped for ~57% of nodes
                int i2 = (ew + 16 < m) ? pv.z : N;
                v2 = *(const bf16x8*)&hbs[(size_t)i2 * DF + f8 * 8];
                if (ms > 24) {   // skipped for ~93% of nodes
                    int i3 = (ew + 24 < m) ? pv.w : N;
                    v3 = *(const bf16x8*)&hbs[(size_t)i3 * DF + f8 * 8];
                }
            }

            float a[8];
            #pragma unroll
            for (int j = 0; j < 8; ++j)
                a[j] = (b2f((unsigned short)v0[j]) + b2f((unsigned short)v1[j]))
                     + (b2f((unsigned short)v2[j]) + b2f((unsigned short)v3[j]));
            #pragma unroll
            for (int msk = 8; msk <= 32; msk <<= 1) {
                #pragma unroll
                for (int j = 0; j < 8; ++j) a[j] += __shfl_xor(a[j], msk);
            }
            if (ew == 0) {
                bf16x8 o;
                #pragma unroll
                for (int j = 0; j < 8; ++j) o[j] = (short)bf16rne(a[j]);
                *(bf16x8*)&csB[ld * CSTR + f8 * 8] = o;
            }
        } else if (ew == 0) {
            bf16x8 z = {0,0,0,0,0,0,0,0};
            *(bf16x8*)&csB[ld * CSTR + f8 * 8] = z;
        }
    }

    // ---- W/b fragments (loaded after phase A to limit live pressure) ----
    const int c = lane & 15, q = lane >> 4;
    bf16x8 bf[4][4];
    #pragma unroll
    for (int nt = 0; nt < 4; ++nt) {
        #pragma unroll
        for (int kt = 0; kt < 4; ++kt) {
            const float* wp = &W[(size_t)(nt * 16 + c) * 128 + kt * 32 + q * 8];
            float4 w0 = *(const float4*)wp;
            float4 w1 = *(const float4*)(wp + 4);
            bf16x8 f;
            f[0] = (short)bf16rne(w0.x); f[1] = (short)bf16rne(w0.y);
            f[2] = (short)bf16rne(w0.z); f[3] = (short)bf16rne(w0.w);
            f[4] = (short)bf16rne(w1.x); f[5] = (short)bf16rne(w1.y);
            f[6] = (short)bf16rne(w1.z); f[7] = (short)bf16rne(w1.w);
            bf[nt][kt] = f;
        }
    }
    float bias[4];
    #pragma unroll
    for (int nt = 0; nt < 4; ++nt) bias[nt] = b[nt * 16 + c];

    int oc = *ovfcnt; if (oc > ovfcap) oc = ovfcap;

    __syncthreads();

    // ---- phase B: wave wv -> tile nodes [wv*16, wv*16+16) ----
    int wn0 = wv * 16;
    int nm = base + wn0 + c;
    int nmc = nm < N ? nm : N - 1;
    int dtot = cnt[nmc];                       // TRUE degree (incl. ovf)
    float inv = 1.0f / fmaxf((float)dtot, 1.0f);

    bf16x8 a0 = *(const bf16x8*)&hbs[(size_t)nmc * DF + q * 8];
    bf16x8 a1 = *(const bf16x8*)&hbs[(size_t)nmc * DF + 32 + q * 8];
    bf16x8 a2, a3;
    #pragma unroll
    for (int kc = 0; kc < 2; ++kc) {
        bf16x8 u = *(const bf16x8*)&csB[(wn0 + c) * CSTR + kc * 32 + q * 8];
        float e[8];
        #pragma unroll
        for (int i = 0; i < 8; ++i) e[i] = b2f((unsigned short)u[i]);
        if (oc > 0) {
            for (int t2 = 0; t2 < oc; ++t2) {
                if (ovf[2 * t2] == nm) {
                    bf16x8 hu = *(const bf16x8*)&hbs[(size_t)ovf[2 * t2 + 1] * DF + kc * 32 + q * 8];
                    #pragma unroll
                    for (int i = 0; i < 8; ++i) e[i] += b2f((unsigned short)hu[i]);
                }
            }
        }
        bf16x8 f;
        #pragma unroll
        for (int i = 0; i < 8; ++i) f[i] = (short)bf16rne(e[i] * inv);
        if (kc == 0) a2 = f; else a3 = f;
    }

    f32x4 acc0 = {bias[0], bias[0], bias[0], bias[0]};
    f32x4 acc1 = {bias[1], bias[1], bias[1], bias[1]};
    f32x4 acc2 = {bias[2], bias[2], bias[2], bias[2]};
    f32x4 acc3 = {bias[3], bias[3], bias[3], bias[3]};
    acc0 = __builtin_amdgcn_mfma_f32_16x16x32_bf16(a0, bf[0][0], acc0, 0, 0, 0);
    acc0 = __builtin_amdgcn_mfma_f32_16x16x32_bf16(a1, bf[0][1], acc0, 0, 0, 0);
    acc0 = __builtin_amdgcn_mfma_f32_16x16x32_bf16(a2, bf[0][2], acc0, 0, 0, 0);
    acc0 = __builtin_amdgcn_mfma_f32_16x16x32_bf16(a3, bf[0][3], acc0, 0, 0, 0);
    acc1 = __builtin_amdgcn_mfma_f32_16x16x32_bf16(a0, bf[1][0], acc1, 0, 0, 0);
    acc1 = __builtin_amdgcn_mfma_f32_16x16x32_bf16(a1, bf[1][1], acc1, 0, 0, 0);
    acc1 = __builtin_amdgcn_mfma_f32_16x16x32_bf16(a2, bf[1][2], acc1, 0, 0, 0);
    acc1 = __builtin_amdgcn_mfma_f32_16x16x32_bf16(a3, bf[1][3], acc1, 0, 0, 0);
    acc2 = __builtin_amdgcn_mfma_f32_16x16x32_bf16(a0, bf[2][0], acc2, 0, 0, 0);
    acc2 = __builtin_amdgcn_mfma_f32_16x16x32_bf16(a1, bf[2][1], acc2, 0, 0, 0);
    acc2 = __builtin_amdgcn_mfma_f32_16x16x32_bf16(a2, bf[2][2], acc2, 0, 0, 0);
    acc2 = __builtin_amdgcn_mfma_f32_16x16x32_bf16(a3, bf[2][3], acc2, 0, 0, 0);
    acc3 = __builtin_amdgcn_mfma_f32_16x16x32_bf16(a0, bf[3][0], acc3, 0, 0, 0);
    acc3 = __builtin_amdgcn_mfma_f32_16x16x32_bf16(a1, bf[3][1], acc3, 0, 0, 0);
    acc3 = __builtin_amdgcn_mfma_f32_16x16x32_bf16(a2, bf[3][2], acc3, 0, 0, 0);
    acc3 = __builtin_amdgcn_mfma_f32_16x16x32_bf16(a3, bf[3][3], acc3, 0, 0, 0);

    float ss[4];
    #pragma unroll
    for (int r = 0; r < 4; ++r)
        ss[r] = acc0[r] * acc0[r] + acc1[r] * acc1[r]
              + acc2[r] * acc2[r] + acc3[r] * acc3[r];
    #pragma unroll
    for (int msk = 1; msk <= 8; msk <<= 1) {
        ss[0] += __shfl_xor(ss[0], msk);
        ss[1] += __shfl_xor(ss[1], msk);
        ss[2] += __shfl_xor(ss[2], msk);
        ss[3] += __shfl_xor(ss[3], msk);
    }
    #pragma unroll
    for (int r = 0; r < 4; ++r) {
        int nr = base + wn0 + q * 4 + r;
        int dr = __shfl(dtot, q * 4 + r);
        if (nr < N) {
            float rin = 1.0f / fmaxf(sqrtf(ss[r]), 1e-12f);
            const float* hp = &h[(size_t)nr * DF + c];
            float hv0 = hp[0], hv1 = hp[16], hv2 = hp[32], hv3 = hp[48];
            bool up = dr > 0;
            float o0 = hv0 + (up ? fmaxf(acc0[r] * rin, 0.f) : hv0);
            float o1 = hv1 + (up ? fmaxf(acc1[r] * rin, 0.f) : hv1);
            float o2 = hv2 + (up ? fmaxf(acc2[r] * rin, 0.f) : hv2);
            float o3 = hv3 + (up ? fmaxf(acc3[r] * rin, 0.f) : hv3);
            float* op = &out[(size_t)nr * DF + c];
            op[0] = o0; op[16] = o1; op[32] = o2; op[48] = o3;
        }
    }
}

extern "C" void kernel_launch(void* const* d_in, const int* in_sizes, int n_in,
                              void* d_out, int out_size, void* d_ws, size_t ws_size,
                              hipStream_t stream) {
    const float* h   = (const float*)d_in[0];
    const float* W   = (const float*)d_in[1];
    const float* b   = (const float*)d_in[2];
    const int*   src = (const int*)d_in[3];
    const int*   dst = (const int*)d_in[4];
    float* out = (float*)d_out;

    const int N = in_sizes[0] / DF;
    const int E = in_sizes[3];

    // workspace carve (16B-aligned)
    int* cnt    = (int*)d_ws;                                // N (true degree)
    int* ovfcnt = cnt + N;                                   // 1 (memset with cnt)
    int* ell    = cnt + ((N + 1 + 15) & ~15);                // N*ELLK
    unsigned short* hbs = (unsigned short*)(ell + (size_t)N * ELLK);  // (N+1)*64
    int* ovf    = (int*)(hbs + (size_t)(N + 1) * DF);
    size_t used = (size_t)((char*)ovf - (char*)d_ws);
    int ovfcap  = (ws_size > used + 64) ? (int)((ws_size - used) / 8 - 4) : 0;

    // K0: zero cnt + ovfcnt (ell needs no zeroing; guarded by cnt)
    hipMemsetAsync(cnt, 0, (size_t)(N + 1) * sizeof(int), stream);

    // K1: bf16 conversion + zero row + direct global-ELL edge scatter
    conv_scatter<<<2048, 512, 0, stream>>>(
        h, src, dst, hbs, cnt, ell, ovf, ovfcnt, ovfcap, N, E);

    // K2: fused gather (LDS csum) + MFMA update
    gather_update<<<(N + WIN - 1) / WIN, 256, 0, stream>>>(
        hbs, cnt, ell, h, W, b, ovf, ovfcnt, ovfcap, out, N);
}

// Round 7
// 186.839 us; speedup vs baseline: 1.6474x; 1.6474x over previous
//
#include <hip/hip_runtime.h>

#define DF 64
#define ELLK 32      // per-node ELL width; local LDS ovf handles deg>32 exactly
#define BSH 9        // bucket = 512-node range (shift, no div)
#define BSTR 9216    // pairs per bucket (avg 8192, sd ~90 -> +11.3 sigma; ovf exact)
#define WIN 128      // nodes per fused block = quarter bucket = 8 MFMA tiles
#define CPAD 68      // csB LDS row stride (bf16), de-banked
#define WPAD 132     // Wl LDS row stride (bf16), de-banked
#define OVL 128      // local ELL-overflow capacity per window

typedef __attribute__((ext_vector_type(8))) short bf16x8;  // MFMA A/B frag
typedef __attribute__((ext_vector_type(4))) float f32x4;   // MFMA C/D frag

__device__ __forceinline__ unsigned short bf16rne(float f) {
    unsigned u = __float_as_uint(f);
    unsigned r = u + 0x7fffu + ((u >> 16) & 1u);
    return (unsigned short)(r >> 16);
}
__device__ __forceinline__ float b2f(unsigned short u) {
    return __uint_as_float((unsigned)u << 16);
}

// ---------------------------------------------------------------------------
// K1: h (fp32) -> hbs row-major bf16 [(N+1)][64] (row N = ZERO sentinel);
// W (fp32 [64][128]) -> Wbs bf16 (once, instead of per-block re-convert);
// zeroes gcur + ovfcnt.
// ---------------------------------------------------------------------------
__global__ __launch_bounds__(256) void conv_zero(
    const float* __restrict__ h, const float* __restrict__ W,
    unsigned short* __restrict__ hbs, unsigned short* __restrict__ Wbs,
    int* __restrict__ gcur, int* __restrict__ ovfcnt, int N)
{
    int tid = blockIdx.x * 256 + threadIdx.x;
    if (tid < 256) gcur[tid] = 0;
    if (tid == 256) *ovfcnt = 0;
    if (tid < 1024) {   // W: 64x128 bf16 in chunks of 8
        int row = tid >> 4, c8 = tid & 15;
        const float* wp = &W[(size_t)row * 128 + c8 * 8];
        float4 w0 = *(const float4*)wp;
        float4 w1 = *(const float4*)(wp + 4);
        bf16x8 f;
        f[0] = (short)bf16rne(w0.x); f[1] = (short)bf16rne(w0.y);
        f[2] = (short)bf16rne(w0.z); f[3] = (short)bf16rne(w0.w);
        f[4] = (short)bf16rne(w1.x); f[5] = (short)bf16rne(w1.y);
        f[6] = (short)bf16rne(w1.z); f[7] = (short)bf16rne(w1.w);
        *(bf16x8*)&Wbs[(size_t)row * 128 + c8 * 8] = f;
    }
    if (tid < (N + 1) * 8) {
        int n = tid >> 3, f8 = tid & 7;
        unsigned short* op = &hbs[(size_t)n * DF + f8 * 8];
        if (n == N) {
            ushort4 z = {0, 0, 0, 0};
            *(ushort4*)op = z; *(ushort4*)(op + 4) = z;
        } else {
            const float* hp = &h[(size_t)n * DF + f8 * 8];
            float4 v0 = *(const float4*)hp;
            float4 v1 = *(const float4*)(hp + 4);
            ushort4 o0, o1;
            o0.x = bf16rne(v0.x); o0.y = bf16rne(v0.y); o0.z = bf16rne(v0.z); o0.w = bf16rne(v0.w);
            o1.x = bf16rne(v1.x); o1.y = bf16rne(v1.y); o1.z = bf16rne(v1.z); o1.w = bf16rne(v1.w);
            *(ushort4*)op = o0;
            *(ushort4*)(op + 4) = o1;
        }
    }
}

// ---------------------------------------------------------------------------
// K2: bin edges into NBK = ceil(N/512) dst-range buckets (bkt = d>>9).
// Per block: LDS histogram -> one global atomicAdd per NON-EMPTY bucket
// (rotated order) reserves an EXCLUSIVE span -> packed u32
// ((d&511)<<17 | src). Span overflow -> global ovf (race-free: only writer).
// ---------------------------------------------------------------------------
#define EPT 13  // edges per thread; per block = 13*256 = 3328
__global__ __launch_bounds__(256) void bin_edges(
    const int* __restrict__ src, const int* __restrict__ dst,
    int* __restrict__ gcur, unsigned* __restrict__ pairs,
    int* __restrict__ ovf, int* __restrict__ ovfcnt, int ovfcap, int E, int N)
{
    __shared__ unsigned hist[256];
    __shared__ unsigned base_s[256];
    int t = threadIdx.x;
    int NBK = (N + 511) >> BSH;
    hist[t] = 0;
    __syncthreads();

    int e0 = blockIdx.x * (EPT * 256);
    unsigned pk[EPT];
    #pragma unroll
    for (int k = 0; k < EPT; ++k) {
        int e = e0 + k * 256 + t;
        pk[k] = 0xFFFFFFFFu;
        if (e < E) {
            int d = dst[e];
            unsigned bkt = (unsigned)d >> BSH;
            unsigned r = atomicAdd(&hist[bkt], 1u);
            pk[k] = (r << 8) | bkt;   // rank < 3328 (12 bits); bkt < 256 (8 bits)
        }
    }
    __syncthreads();
    int rot = (blockIdx.x * 67) % NBK;   // de-phase blocks' atomic order
    if (t < NBK) {
        int ii = t + rot; if (ii >= NBK) ii -= NBK;
        unsigned hv = hist[ii];
        if (hv) base_s[ii] = (unsigned)atomicAdd(&gcur[ii], (int)hv);
    }
    __syncthreads();

    #pragma unroll
    for (int k = 0; k < EPT; ++k) {
        if (pk[k] != 0xFFFFFFFFu) {
            int e = e0 + k * 256 + t;
            int d = dst[e], s = src[e];   // re-read (L1/L2 warm)
            unsigned bkt = pk[k] & 255u;
            unsigned pos = base_s[bkt] + (pk[k] >> 8);
            if (pos < BSTR) {
                pairs[(size_t)bkt * BSTR + pos] =
                    ((unsigned)(d & 511) << 17) | (unsigned)s;
            } else {  // bucket span overflow -> exact fallback list
                int p = atomicAdd(ovfcnt, 1);
                if (p < ovfcap) { ovf[2 * p] = d; ovf[2 * p + 1] = s; }
            }
        }
    }
}

// ---------------------------------------------------------------------------
// K3 (fused build + gather + MFMA update). Block = 128-node window
// (= quarter of one 512-node bucket, exactly 8 MFMA tiles), 512 threads.
//  build : scan bucket pairs (4 sibling blocks share the stream -> L2/L3
//          hits), filter ld into window, int-LDS-atomic ELL insert
//          (permuted cols). ELL-overflow -> LOCAL LDS list (window-owned,
//          race-free). cnt_l = TRUE in-pairs degree.
//  gather: R5's proven loop. Wave = node; 8 lanes/neighbor load the full
//          128 B hbs row; quads 2/3 behind wave-uniform branches; invalid
//          slots clamp to zero row N; 3 shfl_xor; bf16 sum -> csB (LDS;
//          csum never touches global). Invalid nodes write ZERO rows.
//  update: K4 verbatim per wave-tile; W frags stream from LDS Wl (keeps
//          VGPR <= ~85 -> 3 blocks/CU, 24 waves/CU); a2/a3 from csB +
//          global-ovf (span) + local-ovf (deg>32) feature adds; degree =
//          cnt_l + span-ovf matches.
// LDS: 16K ell + 0.5K cnt + 17K csB + 16.5K Wl + 1K ovl  = ~51.5 KB.
// ---------------------------------------------------------------------------
__global__ __launch_bounds__(512, 6) void gather_update(
    const unsigned* __restrict__ pairs, const int* __restrict__ gcur,
    const unsigned short* __restrict__ hbs, const unsigned short* __restrict__ Wbs,
    const float* __restrict__ h, const float* __restrict__ b,
    const int* __restrict__ ovf, const int* __restrict__ ovfcnt,
    int ovfcap, float* __restrict__ out, int N)
{
    __shared__ int ell_l[WIN * ELLK];          // 16 KB
    __shared__ int cnt_l[WIN];
    __shared__ unsigned short csB[WIN * CPAD]; // 17 KB
    __shared__ unsigned short Wl[64 * WPAD];   // 16.5 KB
    __shared__ int ovl[OVL * 2];
    __shared__ int ovn;

    const int t = threadIdx.x, lane = t & 63, wv = t >> 6;
    const int base = blockIdx.x * WIN;
    const int bk = base >> BSH;
    const int q0 = base & 511;

    // init + W -> LDS (bf16 copy with pad)
    for (int i = t; i < WIN; i += 512) cnt_l[i] = 0;
    if (t == 0) ovn = 0;
    for (int i = t; i < 1024; i += 512) {   // 64*128/8 chunks
        int row = i >> 4, c8 = i & 15;
        *(bf16x8*)&Wl[row * WPAD + c8 * 8] =
            *(const bf16x8*)&Wbs[(size_t)row * 128 + c8 * 8];
    }
    __syncthreads();

    // ---- build: filter bucket pairs into window ELL (int LDS atomics) ----
    int count = gcur[bk]; if (count > BSTR) count = BSTR;
    const unsigned* pb = &pairs[(size_t)bk * BSTR];
    for (int i = t; i < count; i += 512) {
        unsigned p = pb[i];
        int ld = (int)(p >> 17) - q0;
        if ((unsigned)ld < (unsigned)WIN) {
            int s = (int)(p & 131071u);
            int slot = atomicAdd(&cnt_l[ld], 1);
            if (slot < ELLK) {
                ell_l[ld * ELLK + (((slot & 7) << 2) | (slot >> 3))] = s;  // permuted
            } else {
                int q2 = atomicAdd(&ovn, 1);
                if (q2 < OVL) { ovl[2 * q2] = ld; ovl[2 * q2 + 1] = s; }
            }
        }
    }
    __syncthreads();

    // ---- gather: wave wv handles nodes [wv*16, wv*16+16) ----
    {
        const int ew = lane >> 3;   // neighbor slot within quad (0..7)
        const int f8 = lane & 7;    // 16 B feat chunk of the 128 B row
        for (int i = 0; i < 16; ++i) {
            int ld = wv * 16 + i;
            int n = base + ld;
            if (n < N) {
                int cv = cnt_l[ld];
                int m = cv < ELLK ? cv : ELLK;
                int ms = __builtin_amdgcn_readfirstlane(m);
                int4 pv = ((const int4*)&ell_l[ld * ELLK])[ew];

                int i0 = (ew     < m) ? pv.x : N;
                int i1 = (ew + 8 < m) ? pv.y : N;
                bf16x8 v0 = *(const bf16x8*)&hbs[(size_t)i0 * DF + f8 * 8];
                bf16x8 v1 = *(const bf16x8*)&hbs[(size_t)i1 * DF + f8 * 8];
                bf16x8 v2 = {0,0,0,0,0,0,0,0};
                bf16x8 v3 = {0,0,0,0,0,0,0,0};
                if (ms > 16) {   // skipped for ~57% of nodes
                    int i2 = (ew + 16 < m) ? pv.z : N;
                    v2 = *(const bf16x8*)&hbs[(size_t)i2 * DF + f8 * 8];
                    if (ms > 24) {   // skipped for ~93% of nodes
                        int i3 = (ew + 24 < m) ? pv.w : N;
                        v3 = *(const bf16x8*)&hbs[(size_t)i3 * DF + f8 * 8];
                    }
                }

                float a[8];
                #pragma unroll
                for (int j = 0; j < 8; ++j)
                    a[j] = (b2f((unsigned short)v0[j]) + b2f((unsigned short)v1[j]))
                         + (b2f((unsigned short)v2[j]) + b2f((unsigned short)v3[j]));
                #pragma unroll
                for (int msk = 8; msk <= 32; msk <<= 1) {
                    #pragma unroll
                    for (int j = 0; j < 8; ++j) a[j] += __shfl_xor(a[j], msk);
                }
                if (ew == 0) {
                    bf16x8 o;
                    #pragma unroll
                    for (int j = 0; j < 8; ++j) o[j] = (short)bf16rne(a[j]);
                    *(bf16x8*)&csB[ld * CPAD + f8 * 8] = o;
                }
            } else if (ew == 0) {   // zero-fill: keeps MFMA inputs finite
                bf16x8 z = {0,0,0,0,0,0,0,0};
                *(bf16x8*)&csB[ld * CPAD + f8 * 8] = z;
            }
        }
    }
    __syncthreads();

    // ---- update: wave wv -> tile nodes [wv*16, wv*16+16) (K4 verbatim) ----
    const int c = lane & 15, q = lane >> 4;
    float bias[4];
    #pragma unroll
    for (int nt = 0; nt < 4; ++nt) bias[nt] = b[nt * 16 + c];

    int oc = *ovfcnt; if (oc > ovfcap) oc = ovfcap;
    int ovnc = ovn; if (ovnc > OVL) ovnc = OVL;

    int wn0 = wv * 16;
    int nm = base + wn0 + c;
    int nmc = nm < N ? nm : N - 1;
    int dtot = cnt_l[wn0 + c];
    if (oc > 0) {
        for (int t2 = 0; t2 < oc; ++t2)
            if (ovf[2 * t2] == nm) dtot++;   // span-ovf: not in cnt_l
    }
    float inv = 1.0f / fmaxf((float)dtot, 1.0f);

    bf16x8 a0 = *(const bf16x8*)&hbs[(size_t)nmc * DF + q * 8];
    bf16x8 a1 = *(const bf16x8*)&hbs[(size_t)nmc * DF + 32 + q * 8];
    bf16x8 a2, a3;
    #pragma unroll
    for (int kc = 0; kc < 2; ++kc) {
        bf16x8 u = *(const bf16x8*)&csB[(wn0 + c) * CPAD + kc * 32 + q * 8];
        float e[8];
        #pragma unroll
        for (int i = 0; i < 8; ++i) e[i] = b2f((unsigned short)u[i]);
        if (oc > 0) {
            for (int t2 = 0; t2 < oc; ++t2) {
                if (ovf[2 * t2] == nm) {
                    bf16x8 hu = *(const bf16x8*)&hbs[(size_t)ovf[2 * t2 + 1] * DF + kc * 32 + q * 8];
                    #pragma unroll
                    for (int i = 0; i < 8; ++i) e[i] += b2f((unsigned short)hu[i]);
                }
            }
        }
        if (ovnc > 0) {
            for (int t2 = 0; t2 < ovnc; ++t2) {
                if (ovl[2 * t2] == wn0 + c) {   // ELL-ovf: counted, not in csB
                    bf16x8 hu = *(const bf16x8*)&hbs[(size_t)ovl[2 * t2 + 1] * DF + kc * 32 + q * 8];
                    #pragma unroll
                    for (int i = 0; i < 8; ++i) e[i] += b2f((unsigned short)hu[i]);
                }
            }
        }
        bf16x8 f;
        #pragma unroll
        for (int i = 0; i < 8; ++i) f[i] = (short)bf16rne(e[i] * inv);
        if (kc == 0) a2 = f; else a3 = f;
    }

    #define WF(nt, kt) (*(const bf16x8*)&Wl[((nt) * 16 + c) * WPAD + (kt) * 32 + q * 8])
    f32x4 acc0 = {bias[0], bias[0], bias[0], bias[0]};
    f32x4 acc1 = {bias[1], bias[1], bias[1], bias[1]};
    f32x4 acc2 = {bias[2], bias[2], bias[2], bias[2]};
    f32x4 acc3 = {bias[3], bias[3], bias[3], bias[3]};
    acc0 = __builtin_amdgcn_mfma_f32_16x16x32_bf16(a0, WF(0,0), acc0, 0, 0, 0);
    acc0 = __builtin_amdgcn_mfma_f32_16x16x32_bf16(a1, WF(0,1), acc0, 0, 0, 0);
    acc0 = __builtin_amdgcn_mfma_f32_16x16x32_bf16(a2, WF(0,2), acc0, 0, 0, 0);
    acc0 = __builtin_amdgcn_mfma_f32_16x16x32_bf16(a3, WF(0,3), acc0, 0, 0, 0);
    acc1 = __builtin_amdgcn_mfma_f32_16x16x32_bf16(a0, WF(1,0), acc1, 0, 0, 0);
    acc1 = __builtin_amdgcn_mfma_f32_16x16x32_bf16(a1, WF(1,1), acc1, 0, 0, 0);
    acc1 = __builtin_amdgcn_mfma_f32_16x16x32_bf16(a2, WF(1,2), acc1, 0, 0, 0);
    acc1 = __builtin_amdgcn_mfma_f32_16x16x32_bf16(a3, WF(1,3), acc1, 0, 0, 0);
    acc2 = __builtin_amdgcn_mfma_f32_16x16x32_bf16(a0, WF(2,0), acc2, 0, 0, 0);
    acc2 = __builtin_amdgcn_mfma_f32_16x16x32_bf16(a1, WF(2,1), acc2, 0, 0, 0);
    acc2 = __builtin_amdgcn_mfma_f32_16x16x32_bf16(a2, WF(2,2), acc2, 0, 0, 0);
    acc2 = __builtin_amdgcn_mfma_f32_16x16x32_bf16(a3, WF(2,3), acc2, 0, 0, 0);
    acc3 = __builtin_amdgcn_mfma_f32_16x16x32_bf16(a0, WF(3,0), acc3, 0, 0, 0);
    acc3 = __builtin_amdgcn_mfma_f32_16x16x32_bf16(a1, WF(3,1), acc3, 0, 0, 0);
    acc3 = __builtin_amdgcn_mfma_f32_16x16x32_bf16(a2, WF(3,2), acc3, 0, 0, 0);
    acc3 = __builtin_amdgcn_mfma_f32_16x16x32_bf16(a3, WF(3,3), acc3, 0, 0, 0);
    #undef WF

    float ss[4];
    #pragma unroll
    for (int r = 0; r < 4; ++r)
        ss[r] = acc0[r] * acc0[r] + acc1[r] * acc1[r]
              + acc2[r] * acc2[r] + acc3[r] * acc3[r];
    #pragma unroll
    for (int msk = 1; msk <= 8; msk <<= 1) {
        ss[0] += __shfl_xor(ss[0], msk);
        ss[1] += __shfl_xor(ss[1], msk);
        ss[2] += __shfl_xor(ss[2], msk);
        ss[3] += __shfl_xor(ss[3], msk);
    }
    #pragma unroll
    for (int r = 0; r < 4; ++r) {
        int nr = base + wn0 + q * 4 + r;
        int dr = __shfl(dtot, q * 4 + r);
        if (nr < N) {
            float rin = 1.0f / fmaxf(sqrtf(ss[r]), 1e-12f);
            const float* hp = &h[(size_t)nr * DF + c];
            float hv0 = hp[0], hv1 = hp[16], hv2 = hp[32], hv3 = hp[48];
            bool up = dr > 0;
            float o0 = hv0 + (up ? fmaxf(acc0[r] * rin, 0.f) : hv0);
            float o1 = hv1 + (up ? fmaxf(acc1[r] * rin, 0.f) : hv1);
            float o2 = hv2 + (up ? fmaxf(acc2[r] * rin, 0.f) : hv2);
            float o3 = hv3 + (up ? fmaxf(acc3[r] * rin, 0.f) : hv3);
            float* op = &out[(size_t)nr * DF + c];
            op[0] = o0; op[16] = o1; op[32] = o2; op[48] = o3;
        }
    }
}

extern "C" void kernel_launch(void* const* d_in, const int* in_sizes, int n_in,
                              void* d_out, int out_size, void* d_ws, size_t ws_size,
                              hipStream_t stream) {
    const float* h   = (const float*)d_in[0];
    const float* W   = (const float*)d_in[1];
    const float* b   = (const float*)d_in[2];
    const int*   src = (const int*)d_in[3];
    const int*   dst = (const int*)d_in[4];
    float* out = (float*)d_out;

    const int N = in_sizes[0] / DF;
    const int E = in_sizes[3];
    const int NBK = (N + 511) >> BSH;

    // workspace carve (16B-aligned)
    int* gcur   = (int*)d_ws;                                // 256
    int* ovfcnt = gcur + 256;                                // 1
    unsigned short* Wbs = (unsigned short*)(gcur + 272);     // 64*128 bf16
    unsigned short* hbs = Wbs + 64 * 128;                    // (N+1)*64 bf16
    unsigned* pairs = (unsigned*)(hbs + (((size_t)(N + 1) * DF + 15) & ~(size_t)15));
    int* ovf    = (int*)(pairs + (size_t)NBK * BSTR);
    size_t used = (size_t)((char*)ovf - (char*)d_ws);
    int ovfcap  = (ws_size > used + 64) ? (int)((ws_size - used) / 8 - 4) : 0;

    // K1: bf16 conversions (h + W) + zero row + cursor zeroing
    conv_zero<<<((N + 1) * 8 + 255) / 256, 256, 0, stream>>>(
        h, W, hbs, Wbs, gcur, ovfcnt, N);

    // K2: bin edges into 512-node-range buckets (shift-based)
    bin_edges<<<(E + EPT * 256 - 1) / (EPT * 256), 256, 0, stream>>>(
        src, dst, gcur, pairs, ovf, ovfcnt, ovfcap, E, N);

    // K3: fused build + gather + MFMA update (one block per 128-node window)
    gather_update<<<(N + WIN - 1) / WIN, 512, 0, stream>>>(
        pairs, gcur, hbs, Wbs, h, b, ovf, ovfcnt, ovfcap, out, N);
}

// Round 8
// 183.127 us; speedup vs baseline: 1.6808x; 1.0203x over previous
//
#include <hip/hip_runtime.h>

#define DF 64
#define ELLK 32      // per-node ELL width; LDS ovl handles deg>32 exactly
#define BSH 9        // bucket = 512-node dst range
#define WIN 128      // nodes per fused block = quarter bucket = 8 MFMA tiles
#define CAP 64       // pairs slots per (bin-block, bucket); mean 17, +11 sigma
#define OCAP 32      // per-bin-block chunk-overflow entries (u64)
#define WPAD 132     // Wl LDS row stride (bf16), de-banked
#define OVL 128      // per-window ELL-overflow capacity
#define EPT 13       // edges per bin thread; 13*256 = 3328/block
#define MAXCH 512    // compile-time bound on bin-block count (actual 481)

typedef __attribute__((ext_vector_type(8))) short bf16x8;  // MFMA A/B frag
typedef __attribute__((ext_vector_type(4))) float f32x4;   // MFMA C/D frag

__device__ __forceinline__ unsigned short bf16rne(float f) {
    unsigned u = __float_as_uint(f);
    unsigned r = u + 0x7fffu + ((u >> 16) & 1u);
    return (unsigned short)(r >> 16);
}
__device__ __forceinline__ float b2f(unsigned short u) {
    return __uint_as_float((unsigned)u << 16);
}

// ---------------------------------------------------------------------------
// K1 (fused conv + bin). No pre-zeroed state needed anywhere:
//  conv : h (fp32) -> hbs bf16 [(N+1)][64] (row N = ZERO sentinel) and
//         W -> Wbs bf16, grid-strided.
//  bin  : LDS histogram over NBK=ceil(N/512) dst-range buckets (bkt=d>>9),
//         then each block writes its bucket-k pairs into its OWN fixed
//         chunk pairs[(k*NCH + blk)*CAP + rank] (no cross-block atomics,
//         no reservation pass). bcnt[blk*NBK+k] = clamped count. rank>=CAP
//         -> per-block ovfb list (u64 d<<32|src), count in bovn[blk].
// ---------------------------------------------------------------------------
__global__ __launch_bounds__(256) void conv_bin(
    const float* __restrict__ h, const float* __restrict__ W,
    const int* __restrict__ src, const int* __restrict__ dst,
    unsigned short* __restrict__ hbs, unsigned short* __restrict__ Wbs,
    unsigned* __restrict__ pairs, int* __restrict__ bcnt,
    unsigned long long* __restrict__ ovfb, int* __restrict__ bovn,
    int N, int E, int NBK, int NCH)
{
    __shared__ unsigned hist[256];
    __shared__ int ovn_l;
    const int t = threadIdx.x;
    hist[t] = 0;
    if (t == 0) ovn_l = 0;

    // ---- conv work (grid-stride): 1024 W chunks + (N+1)*8 h chunks ----
    int tot = 1024 + (N + 1) * 8;
    for (int i = blockIdx.x * 256 + t; i < tot; i += gridDim.x * 256) {
        if (i < 1024) {
            int row = i >> 4, c8 = i & 15;
            const float* wp = &W[(size_t)row * 128 + c8 * 8];
            float4 w0 = *(const float4*)wp;
            float4 w1 = *(const float4*)(wp + 4);
            bf16x8 f;
            f[0] = (short)bf16rne(w0.x); f[1] = (short)bf16rne(w0.y);
            f[2] = (short)bf16rne(w0.z); f[3] = (short)bf16rne(w0.w);
            f[4] = (short)bf16rne(w1.x); f[5] = (short)bf16rne(w1.y);
            f[6] = (short)bf16rne(w1.z); f[7] = (short)bf16rne(w1.w);
            *(bf16x8*)&Wbs[(size_t)row * 128 + c8 * 8] = f;
        } else {
            int j = i - 1024;
            int n = j >> 3, f8 = j & 7;
            unsigned short* op = &hbs[(size_t)n * DF + f8 * 8];
            if (n == N) {
                ushort4 z = {0, 0, 0, 0};
                *(ushort4*)op = z; *(ushort4*)(op + 4) = z;
            } else {
                const float* hp = &h[(size_t)n * DF + f8 * 8];
                float4 v0 = *(const float4*)hp;
                float4 v1 = *(const float4*)(hp + 4);
                ushort4 o0, o1;
                o0.x = bf16rne(v0.x); o0.y = bf16rne(v0.y);
                o0.z = bf16rne(v0.z); o0.w = bf16rne(v0.w);
                o1.x = bf16rne(v1.x); o1.y = bf16rne(v1.y);
                o1.z = bf16rne(v1.z); o1.w = bf16rne(v1.w);
                *(ushort4*)op = o0;
                *(ushort4*)(op + 4) = o1;
            }
        }
    }
    __syncthreads();

    // ---- bin pass 1: histogram + per-edge rank ----
    int e0 = blockIdx.x * (EPT * 256);
    unsigned pk[EPT];
    #pragma unroll
    for (int k = 0; k < EPT; ++k) {
        int e = e0 + k * 256 + t;
        pk[k] = 0xFFFFFFFFu;
        if (e < E) {
            int d = dst[e];
            unsigned bkt = (unsigned)d >> BSH;
            unsigned r = atomicAdd(&hist[bkt], 1u);
            pk[k] = (r << 8) | bkt;   // rank < 3328 (24 bits ok); bkt < 256
        }
    }
    __syncthreads();

    // ---- bin pass 2: write into own fixed chunks (no atomics) ----
    #pragma unroll
    for (int k = 0; k < EPT; ++k) {
        if (pk[k] != 0xFFFFFFFFu) {
            int e = e0 + k * 256 + t;
            int d = dst[e], s = src[e];   // re-read (L1/L2 warm)
            unsigned bkt = pk[k] & 255u;
            unsigned r = pk[k] >> 8;
            if (r < CAP) {
                pairs[((size_t)bkt * NCH + blockIdx.x) * CAP + r] =
                    ((unsigned)(d & 511) << 17) | (unsigned)s;
            } else {   // chunk overflow -> exact per-block list
                int p = atomicAdd(&ovn_l, 1);
                if (p < OCAP)
                    ovfb[(size_t)blockIdx.x * OCAP + p] =
                        ((unsigned long long)(unsigned)d << 32) | (unsigned)s;
            }
        }
    }
    __syncthreads();
    if (t < NBK) {
        unsigned c = hist[t];
        bcnt[(size_t)blockIdx.x * NBK + t] = (int)(c < CAP ? c : CAP);
    }
    if (t == 0) bovn[blockIdx.x] = (ovn_l < OCAP ? ovn_l : OCAP);
}

// ---------------------------------------------------------------------------
// K2 (fused build + gather + MFMA update). Block = 128-node window, 512 thr,
// LDS ~36.9 KB -> 4 blocks/CU, grid 782 fully co-resident (no tail).
//  build : wave-iter = one chunk of this window's bucket: lane < cnt ->
//          one coalesced pair read; filter ld into window; int-LDS-atomic
//          ELL insert (permuted cols). deg>32 -> LDS ovl. Then rescan
//          bovn/ovfb (chunk-capacity overflow; ~always empty).
//  gather: wave = node; 8 lanes/neighbor load the full 128 B hbs row;
//          quads 2/3 behind wave-uniform branches; invalid slots clamp to
//          zero row N; 3 shfl_xor. Sum row (128 B) written back INTO the
//          node's own ell_l row (read-before-write in program order),
//          XOR slot-swizzled (sl = f8 ^ (ld&7)) for bank-free phase-B read.
//  update: per wave-tile MFMA; W frags from LDS Wl; a2/a3 from the reused
//          ell_l rows + ovl feature adds; dtot = cnt_l (true degree).
// ---------------------------------------------------------------------------
__global__ __launch_bounds__(512, 8) void gather_update(
    const unsigned* __restrict__ pairs, const int* __restrict__ bcnt,
    const unsigned long long* __restrict__ ovfb, const int* __restrict__ bovn,
    const unsigned short* __restrict__ hbs, const unsigned short* __restrict__ Wbs,
    const float* __restrict__ h, const float* __restrict__ b,
    float* __restrict__ out, int N, int NBK, int NCH)
{
    __shared__ int ell_l[WIN * ELLK];          // 16 KB; reused as csum rows
    __shared__ int cnt_l[WIN];                 // 0.5 KB
    __shared__ unsigned short Wl[64 * WPAD];   // 16.9 KB
    __shared__ int bcnt_l[MAXCH];              // 2 KB
    __shared__ int ovl[OVL * 2];               // 1 KB
    __shared__ int ovn;

    const int t = threadIdx.x, lane = t & 63, wv = t >> 6;
    const int base = blockIdx.x * WIN;
    const int bk = base >> BSH;
    const int q0 = base & 511;

    for (int i = t; i < WIN; i += 512) cnt_l[i] = 0;
    if (t == 0) ovn = 0;
    for (int i = t; i < 1024; i += 512) {   // W -> LDS (padded)
        int row = i >> 4, c8 = i & 15;
        *(bf16x8*)&Wl[row * WPAD + c8 * 8] =
            *(const bf16x8*)&Wbs[(size_t)row * 128 + c8 * 8];
    }
    for (int i = t; i < NCH; i += 512)
        bcnt_l[i] = bcnt[(size_t)i * NBK + bk];
    __syncthreads();

    // ---- build: one chunk per wave-iter, coalesced ----
    for (int ch = wv; ch < NCH; ch += 8) {
        int cc = bcnt_l[ch];
        if (lane < cc) {
            unsigned p = pairs[((size_t)bk * NCH + ch) * CAP + lane];
            int ld = (int)(p >> 17) - q0;
            if ((unsigned)ld < (unsigned)WIN) {
                int s = (int)(p & 131071u);
                int slot = atomicAdd(&cnt_l[ld], 1);
                if (slot < ELLK) {
                    ell_l[ld * ELLK + (((slot & 7) << 2) | (slot >> 3))] = s;
                } else {
                    int q2 = atomicAdd(&ovn, 1);
                    if (q2 < OVL) { ovl[2 * q2] = ld; ovl[2 * q2 + 1] = s; }
                }
            }
        }
    }
    // chunk-capacity overflow rescan (~always empty)
    for (int i = t; i < NCH; i += 512) {
        int bn = bovn[i];
        for (int j = 0; j < bn; ++j) {
            unsigned long long v = ovfb[(size_t)i * OCAP + j];
            int d = (int)(v >> 32);
            int ld = d - base;
            if ((unsigned)ld < (unsigned)WIN) {
                int s = (int)(v & 0xFFFFFFFFu);
                int slot = atomicAdd(&cnt_l[ld], 1);
                if (slot < ELLK) {
                    ell_l[ld * ELLK + (((slot & 7) << 2) | (slot >> 3))] = s;
                } else {
                    int q2 = atomicAdd(&ovn, 1);
                    if (q2 < OVL) { ovl[2 * q2] = ld; ovl[2 * q2 + 1] = s; }
                }
            }
        }
    }
    __syncthreads();

    // ---- gather: wave wv owns nodes [wv*16, wv*16+16) ----
    unsigned short* csB = (unsigned short*)ell_l;   // reuse: sum rows
    {
        const int ew = lane >> 3;   // neighbor slot within quad (0..7)
        const int f8 = lane & 7;    // 16 B feat chunk of the 128 B row
        for (int i = 0; i < 16; ++i) {
            int ld = wv * 16 + i;
            int n = base + ld;
            if (n < N) {
                int cv = cnt_l[ld];
                int m = cv < ELLK ? cv : ELLK;
                int ms = __builtin_amdgcn_readfirstlane(m);
                int4 pv = ((const int4*)&ell_l[ld * ELLK])[ew];  // read BEFORE write-back

                int i0 = (ew     < m) ? pv.x : N;
                int i1 = (ew + 8 < m) ? pv.y : N;
                bf16x8 v0 = *(const bf16x8*)&hbs[(size_t)i0 * DF + f8 * 8];
                bf16x8 v1 = *(const bf16x8*)&hbs[(size_t)i1 * DF + f8 * 8];
                bf16x8 v2 = {0,0,0,0,0,0,0,0};
                bf16x8 v3 = {0,0,0,0,0,0,0,0};
                if (ms > 16) {   // skipped for ~57% of nodes
                    int i2 = (ew + 16 < m) ? pv.z : N;
                    v2 = *(const bf16x8*)&hbs[(size_t)i2 * DF + f8 * 8];
                    if (ms > 24) {   // skipped for ~93% of nodes
                        int i3 = (ew + 24 < m) ? pv.w : N;
                        v3 = *(const bf16x8*)&hbs[(size_t)i3 * DF + f8 * 8];
                    }
                }

                float a[8];
                #pragma unroll
                for (int j = 0; j < 8; ++j)
                    a[j] = (b2f((unsigned short)v0[j]) + b2f((unsigned short)v1[j]))
                         + (b2f((unsigned short)v2[j]) + b2f((unsigned short)v3[j]));
                #pragma unroll
                for (int msk = 8; msk <= 32; msk <<= 1) {
                    #pragma unroll
                    for (int j = 0; j < 8; ++j) a[j] += __shfl_xor(a[j], msk);
                }
                if (ew == 0) {   // write-back into own row, slot-swizzled
                    bf16x8 o;
                    #pragma unroll
                    for (int j = 0; j < 8; ++j) o[j] = (short)bf16rne(a[j]);
                    int sl = f8 ^ (ld & 7);
                    *(bf16x8*)&csB[ld * 64 + sl * 8] = o;
                }
            } else if (ew == 0) {   // zero-fill invalid node rows
                bf16x8 z = {0,0,0,0,0,0,0,0};
                int sl = f8 ^ (ld & 7);
                *(bf16x8*)&csB[ld * 64 + sl * 8] = z;
            }
        }
    }
    __syncthreads();

    // ---- update: wave wv -> tile nodes [wv*16, wv*16+16) ----
    const int c = lane & 15, q = lane >> 4;
    float bias[4];
    #pragma unroll
    for (int nt = 0; nt < 4; ++nt) bias[nt] = b[nt * 16 + c];

    int ovnc = ovn; if (ovnc > OVL) ovnc = OVL;

    int wn0 = wv * 16;
    int nm = base + wn0 + c;
    int nmc = nm < N ? nm : N - 1;
    int dtot = cnt_l[wn0 + c];                 // TRUE degree
    float inv = 1.0f / fmaxf((float)dtot, 1.0f);

    bf16x8 a0 = *(const bf16x8*)&hbs[(size_t)nmc * DF + q * 8];
    bf16x8 a1 = *(const bf16x8*)&hbs[(size_t)nmc * DF + 32 + q * 8];
    bf16x8 a2, a3;
    #pragma unroll
    for (int kc = 0; kc < 2; ++kc) {
        int srow = wn0 + c;
        int sl = (kc * 4 + q) ^ (srow & 7);    // inverse of the write swizzle
        bf16x8 u = *(const bf16x8*)&csB[srow * 64 + sl * 8];
        float e[8];
        #pragma unroll
        for (int i = 0; i < 8; ++i) e[i] = b2f((unsigned short)u[i]);
        if (ovnc > 0) {
            for (int t2 = 0; t2 < ovnc; ++t2) {
                if (ovl[2 * t2] == wn0 + c) {  // deg>32 extras (counted in dtot)
                    bf16x8 hu = *(const bf16x8*)&hbs[(size_t)ovl[2 * t2 + 1] * DF + kc * 32 + q * 8];
                    #pragma unroll
                    for (int i = 0; i < 8; ++i) e[i] += b2f((unsigned short)hu[i]);
                }
            }
        }
        bf16x8 f;
        #pragma unroll
        for (int i = 0; i < 8; ++i) f[i] = (short)bf16rne(e[i] * inv);
        if (kc == 0) a2 = f; else a3 = f;
    }

    #define WF(nt, kt) (*(const bf16x8*)&Wl[((nt) * 16 + c) * WPAD + (kt) * 32 + q * 8])
    f32x4 acc0 = {bias[0], bias[0], bias[0], bias[0]};
    f32x4 acc1 = {bias[1], bias[1], bias[1], bias[1]};
    f32x4 acc2 = {bias[2], bias[2], bias[2], bias[2]};
    f32x4 acc3 = {bias[3], bias[3], bias[3], bias[3]};
    acc0 = __builtin_amdgcn_mfma_f32_16x16x32_bf16(a0, WF(0,0), acc0, 0, 0, 0);
    acc0 = __builtin_amdgcn_mfma_f32_16x16x32_bf16(a1, WF(0,1), acc0, 0, 0, 0);
    acc0 = __builtin_amdgcn_mfma_f32_16x16x32_bf16(a2, WF(0,2), acc0, 0, 0, 0);
    acc0 = __builtin_amdgcn_mfma_f32_16x16x32_bf16(a3, WF(0,3), acc0, 0, 0, 0);
    acc1 = __builtin_amdgcn_mfma_f32_16x16x32_bf16(a0, WF(1,0), acc1, 0, 0, 0);
    acc1 = __builtin_amdgcn_mfma_f32_16x16x32_bf16(a1, WF(1,1), acc1, 0, 0, 0);
    acc1 = __builtin_amdgcn_mfma_f32_16x16x32_bf16(a2, WF(1,2), acc1, 0, 0, 0);
    acc1 = __builtin_amdgcn_mfma_f32_16x16x32_bf16(a3, WF(1,3), acc1, 0, 0, 0);
    acc2 = __builtin_amdgcn_mfma_f32_16x16x32_bf16(a0, WF(2,0), acc2, 0, 0, 0);
    acc2 = __builtin_amdgcn_mfma_f32_16x16x32_bf16(a1, WF(2,1), acc2, 0, 0, 0);
    acc2 = __builtin_amdgcn_mfma_f32_16x16x32_bf16(a2, WF(2,2), acc2, 0, 0, 0);
    acc2 = __builtin_amdgcn_mfma_f32_16x16x32_bf16(a3, WF(2,3), acc2, 0, 0, 0);
    acc3 = __builtin_amdgcn_mfma_f32_16x16x32_bf16(a0, WF(3,0), acc3, 0, 0, 0);
    acc3 = __builtin_amdgcn_mfma_f32_16x16x32_bf16(a1, WF(3,1), acc3, 0, 0, 0);
    acc3 = __builtin_amdgcn_mfma_f32_16x16x32_bf16(a2, WF(3,2), acc3, 0, 0, 0);
    acc3 = __builtin_amdgcn_mfma_f32_16x16x32_bf16(a3, WF(3,3), acc3, 0, 0, 0);
    #undef WF

    float ss[4];
    #pragma unroll
    for (int r = 0; r < 4; ++r)
        ss[r] = acc0[r] * acc0[r] + acc1[r] * acc1[r]
              + acc2[r] * acc2[r] + acc3[r] * acc3[r];
    #pragma unroll
    for (int msk = 1; msk <= 8; msk <<= 1) {
        ss[0] += __shfl_xor(ss[0], msk);
        ss[1] += __shfl_xor(ss[1], msk);
        ss[2] += __shfl_xor(ss[2], msk);
        ss[3] += __shfl_xor(ss[3], msk);
    }
    #pragma unroll
    for (int r = 0; r < 4; ++r) {
        int nr = base + wn0 + q * 4 + r;
        int dr = __shfl(dtot, q * 4 + r);
        if (nr < N) {
            float rin = 1.0f / fmaxf(sqrtf(ss[r]), 1e-12f);
            const float* hp = &h[(size_t)nr * DF + c];
            float hv0 = hp[0], hv1 = hp[16], hv2 = hp[32], hv3 = hp[48];
            bool up = dr > 0;
            float o0 = hv0 + (up ? fmaxf(acc0[r] * rin, 0.f) : hv0);
            float o1 = hv1 + (up ? fmaxf(acc1[r] * rin, 0.f) : hv1);
            float o2 = hv2 + (up ? fmaxf(acc2[r] * rin, 0.f) : hv2);
            float o3 = hv3 + (up ? fmaxf(acc3[r] * rin, 0.f) : hv3);
            float* op = &out[(size_t)nr * DF + c];
            op[0] = o0; op[16] = o1; op[32] = o2; op[48] = o3;
        }
    }
}

extern "C" void kernel_launch(void* const* d_in, const int* in_sizes, int n_in,
                              void* d_out, int out_size, void* d_ws, size_t ws_size,
                              hipStream_t stream) {
    const float* h   = (const float*)d_in[0];
    const float* W   = (const float*)d_in[1];
    const float* b   = (const float*)d_in[2];
    const int*   src = (const int*)d_in[3];
    const int*   dst = (const int*)d_in[4];
    float* out = (float*)d_out;

    const int N = in_sizes[0] / DF;
    const int E = in_sizes[3];
    const int NBK = (N + 511) >> BSH;                 // 196
    const int NCH = (E + EPT * 256 - 1) / (EPT * 256); // 481 (<= MAXCH)

    // workspace carve (16B-aligned); no pre-zeroing needed anywhere
    unsigned short* Wbs = (unsigned short*)d_ws;                       // 64*128
    unsigned short* hbs = Wbs + 64 * 128;                              // (N+1)*64
    unsigned* pairs = (unsigned*)(hbs + (((size_t)(N + 1) * DF + 15) & ~(size_t)15));
    int* bcnt = (int*)(pairs + (size_t)NBK * NCH * CAP);               // NCH*NBK
    int* bovn = bcnt + (((size_t)NCH * NBK + 15) & ~(size_t)15);       // NCH
    unsigned long long* ovfb =
        (unsigned long long*)(bovn + ((NCH + 15) & ~15));              // NCH*OCAP

    // K1: fused bf16 conversions + edge binning (fixed per-block chunks)
    conv_bin<<<NCH, 256, 0, stream>>>(
        h, W, src, dst, hbs, Wbs, pairs, bcnt, ovfb, bovn, N, E, NBK, NCH);

    // K2: fused build + gather + MFMA update (782 blocks, 4/CU, no tail)
    gather_update<<<(N + WIN - 1) / WIN, 512, 0, stream>>>(
        pairs, bcnt, ovfb, bovn, hbs, Wbs, h, b, out, N, NBK, NCH);
}

// Round 10
// 174.068 us; speedup vs baseline: 1.7683x; 1.0520x over previous
//
#include <hip/hip_runtime.h>

#define DF 64
#define ELLK 32      // per-node ELL width; LDS ovl handles deg>32 exactly
#define BSH 9        // bucket = 512-node dst range
#define WIN 128      // nodes per fused block = quarter bucket = 8 MFMA tiles
#define CAP 32       // pairs slots per (bin-block, bucket) cell = one 128 B line
#define OCAP 32      // per-bin-block chunk-overflow entries (u64); exact fallback
#define WPAD 132     // Wl LDS row stride (bf16), de-banked
#define OVL 128      // per-window ELL-overflow capacity
#define MAXCH 800    // compile-time bound on bin-block count (actual ~782)

typedef __attribute__((ext_vector_type(8))) short bf16x8;  // MFMA A/B frag
typedef __attribute__((ext_vector_type(4))) float f32x4;   // MFMA C/D frag

__device__ __forceinline__ unsigned short bf16rne(float f) {
    unsigned u = __float_as_uint(f);
    unsigned r = u + 0x7fffu + ((u >> 16) & 1u);
    return (unsigned short)(r >> 16);
}
__device__ __forceinline__ float b2f(unsigned short u) {
    return __uint_as_float((unsigned)u << 16);
}

// ---------------------------------------------------------------------------
// K1 (fused conv + SINGLE-PASS bin), 512 thr x NCH blocks (~4 blocks/CU):
//  conv : h -> hbs bf16 [(N+1)][64] (row N = zero sentinel), W -> Wbs,
//         grid-strided.
//  bin  : one pass over own edge range; the LDS-histogram rank IS the chunk
//         slot: pairs[(bkt*NCH + blk)*CAP + r]. r >= CAP -> per-block ovfb
//         (u64 d<<32|src). bcnt stored TRANSPOSED [NBK][NCH] so K2's read
//         is coalesced. No pre-zeroed global state needed.
// ---------------------------------------------------------------------------
__global__ __launch_bounds__(512) void conv_bin(
    const float* __restrict__ h, const float* __restrict__ W,
    const int* __restrict__ src, const int* __restrict__ dst,
    unsigned short* __restrict__ hbs, unsigned short* __restrict__ Wbs,
    unsigned* __restrict__ pairs, int* __restrict__ bcnt,
    unsigned long long* __restrict__ ovfb, int* __restrict__ bovn,
    int N, int E, int NBK, int NCH, int EPB)
{
    __shared__ unsigned hist[256];
    __shared__ int ovn_l;
    const int t = threadIdx.x, blk = blockIdx.x;
    if (t < 256) hist[t] = 0;
    if (t == 0) ovn_l = 0;
    __syncthreads();

    // ---- conv (grid-stride): 1024 W chunks + (N+1)*8 h chunks ----
    int tot = 1024 + (N + 1) * 8;
    for (int i = blk * 512 + t; i < tot; i += NCH * 512) {
        if (i < 1024) {
            int row = i >> 4, c8 = i & 15;
            const float* wp = &W[(size_t)row * 128 + c8 * 8];
            float4 w0 = *(const float4*)wp;
            float4 w1 = *(const float4*)(wp + 4);
            bf16x8 f;
            f[0] = (short)bf16rne(w0.x); f[1] = (short)bf16rne(w0.y);
            f[2] = (short)bf16rne(w0.z); f[3] = (short)bf16rne(w0.w);
            f[4] = (short)bf16rne(w1.x); f[5] = (short)bf16rne(w1.y);
            f[6] = (short)bf16rne(w1.z); f[7] = (short)bf16rne(w1.w);
            *(bf16x8*)&Wbs[(size_t)row * 128 + c8 * 8] = f;
        } else {
            int j = i - 1024;
            int n = j >> 3, f8 = j & 7;
            unsigned short* op = &hbs[(size_t)n * DF + f8 * 8];
            if (n == N) {
                ushort4 z = {0, 0, 0, 0};
                *(ushort4*)op = z; *(ushort4*)(op + 4) = z;
            } else {
                const float* hp = &h[(size_t)n * DF + f8 * 8];
                float4 v0 = *(const float4*)hp;
                float4 v1 = *(const float4*)(hp + 4);
                ushort4 o0, o1;
                o0.x = bf16rne(v0.x); o0.y = bf16rne(v0.y);
                o0.z = bf16rne(v0.z); o0.w = bf16rne(v0.w);
                o1.x = bf16rne(v1.x); o1.y = bf16rne(v1.y);
                o1.z = bf16rne(v1.z); o1.w = bf16rne(v1.w);
                *(ushort4*)op = o0;
                *(ushort4*)(op + 4) = o1;
            }
        }
    }

    // ---- bin own edge range, single pass (rank = chunk slot) ----
    int e0 = blk * EPB, e1 = e0 + EPB; if (e1 > E) e1 = E;
    for (int e = e0 + t; e < e1; e += 512) {
        int d = dst[e], s = src[e];
        unsigned bkt = (unsigned)d >> BSH;
        unsigned r = atomicAdd(&hist[bkt], 1u);
        if (r < CAP) {
            pairs[((size_t)bkt * NCH + blk) * CAP + r] =
                ((unsigned)(d & 511) << 17) | (unsigned)s;
        } else {   // chunk overflow -> exact per-block list
            int p = atomicAdd(&ovn_l, 1);
            if (p < OCAP)
                ovfb[(size_t)blk * OCAP + p] =
                    ((unsigned long long)(unsigned)d << 32) | (unsigned)s;
        }
    }
    __syncthreads();
    for (int i = t; i < NBK; i += 512) {
        unsigned c = hist[i];
        bcnt[(size_t)i * NCH + blk] = (int)(c < CAP ? c : CAP);  // [NBK][NCH]
    }
    if (t == 0) bovn[blk] = (ovn_l < OCAP ? ovn_l : OCAP);
}

// ---------------------------------------------------------------------------
// K2 (fused build + gather + MFMA update) — R8 structure verbatim, plus:
// transposed bcnt read (coalesced) and 2-chunks-per-wave build (CAP=32).
// Block = 128-node window, 512 thr, LDS ~37.6 KB -> 4 blocks/CU, grid 782
// fully co-resident (no tail).
// ---------------------------------------------------------------------------
__global__ __launch_bounds__(512, 8) void gather_update(
    const unsigned* __restrict__ pairs, const int* __restrict__ bcnt,
    const unsigned long long* __restrict__ ovfb, const int* __restrict__ bovn,
    const unsigned short* __restrict__ hbs, const unsigned short* __restrict__ Wbs,
    const float* __restrict__ h, const float* __restrict__ b,
    float* __restrict__ out, int N, int NBK, int NCH)
{
    __shared__ int ell_l[WIN * ELLK];          // 16 KB; reused as csum rows
    __shared__ int cnt_l[WIN];                 // 0.5 KB
    __shared__ unsigned short Wl[64 * WPAD];   // 16.9 KB
    __shared__ int bcnt_l[MAXCH];              // 3.2 KB
    __shared__ int ovl[OVL * 2];               // 1 KB
    __shared__ int ovn;

    const int t = threadIdx.x, lane = t & 63, wv = t >> 6;
    const int base = blockIdx.x * WIN;
    const int bk = base >> BSH;
    const int q0 = base & 511;

    for (int i = t; i < WIN; i += 512) cnt_l[i] = 0;
    if (t == 0) ovn = 0;
    for (int i = t; i < 1024; i += 512) {   // W -> LDS (padded)
        int row = i >> 4, c8 = i & 15;
        *(bf16x8*)&Wl[row * WPAD + c8 * 8] =
            *(const bf16x8*)&Wbs[(size_t)row * 128 + c8 * 8];
    }
    for (int i = t; i < NCH; i += 512)
        bcnt_l[i] = bcnt[(size_t)bk * NCH + i];   // coalesced (transposed layout)
    __syncthreads();

    // ---- build: 2 chunks per wave-iter (32-lane halves match CAP=32) ----
    int nit = (NCH + 15) >> 4;   // 16 chunks per block-iter (2/wave x 8 waves)
    for (int it = 0; it < nit; ++it) {
        int ch = it * 16 + wv * 2 + (lane >> 5);
        int slot = lane & 31;
        if (ch < NCH && slot < bcnt_l[ch]) {
            unsigned p = pairs[((size_t)bk * NCH + ch) * CAP + slot];
            int ld = (int)(p >> 17) - q0;
            if ((unsigned)ld < (unsigned)WIN) {
                int s = (int)(p & 131071u);
                int sl2 = atomicAdd(&cnt_l[ld], 1);
                if (sl2 < ELLK) {
                    ell_l[ld * ELLK + (((sl2 & 7) << 2) | (sl2 >> 3))] = s;
                } else {
                    int q2 = atomicAdd(&ovn, 1);
                    if (q2 < OVL) { ovl[2 * q2] = ld; ovl[2 * q2 + 1] = s; }
                }
            }
        }
    }
    // chunk-capacity overflow rescan (~always empty)
    for (int i = t; i < NCH; i += 512) {
        int bn = bovn[i];
        for (int j = 0; j < bn; ++j) {
            unsigned long long v = ovfb[(size_t)i * OCAP + j];
            int d = (int)(v >> 32);
            int ld = d - base;
            if ((unsigned)ld < (unsigned)WIN) {
                int s = (int)(v & 0xFFFFFFFFu);
                int sl2 = atomicAdd(&cnt_l[ld], 1);
                if (sl2 < ELLK) {
                    ell_l[ld * ELLK + (((sl2 & 7) << 2) | (sl2 >> 3))] = s;
                } else {
                    int q2 = atomicAdd(&ovn, 1);
                    if (q2 < OVL) { ovl[2 * q2] = ld; ovl[2 * q2 + 1] = s; }
                }
            }
        }
    }
    __syncthreads();

    // ---- gather: wave wv owns nodes [wv*16, wv*16+16) ----
    unsigned short* csB = (unsigned short*)ell_l;   // reuse: sum rows
    {
        const int ew = lane >> 3;   // neighbor slot within quad (0..7)
        const int f8 = lane & 7;    // 16 B feat chunk of the 128 B row
        for (int i = 0; i < 16; ++i) {
            int ld = wv * 16 + i;
            int n = base + ld;
            if (n < N) {
                int cv = cnt_l[ld];
                int m = cv < ELLK ? cv : ELLK;
                int ms = __builtin_amdgcn_readfirstlane(m);
                int4 pv = ((const int4*)&ell_l[ld * ELLK])[ew];  // read BEFORE write-back

                int i0 = (ew     < m) ? pv.x : N;
                int i1 = (ew + 8 < m) ? pv.y : N;
                bf16x8 v0 = *(const bf16x8*)&hbs[(size_t)i0 * DF + f8 * 8];
                bf16x8 v1 = *(const bf16x8*)&hbs[(size_t)i1 * DF + f8 * 8];
                bf16x8 v2 = {0,0,0,0,0,0,0,0};
                bf16x8 v3 = {0,0,0,0,0,0,0,0};
                if (ms > 16) {   // skipped for ~57% of nodes
                    int i2 = (ew + 16 < m) ? pv.z : N;
                    v2 = *(const bf16x8*)&hbs[(size_t)i2 * DF + f8 * 8];
                    if (ms > 24) {   // skipped for ~93% of nodes
                        int i3 = (ew + 24 < m) ? pv.w : N;
                        v3 = *(const bf16x8*)&hbs[(size_t)i3 * DF + f8 * 8];
                    }
                }

                float a[8];
                #pragma unroll
                for (int j = 0; j < 8; ++j)
                    a[j] = (b2f((unsigned short)v0[j]) + b2f((unsigned short)v1[j]))
                         + (b2f((unsigned short)v2[j]) + b2f((unsigned short)v3[j]));
                #pragma unroll
                for (int msk = 8; msk <= 32; msk <<= 1) {
                    #pragma unroll
                    for (int j = 0; j < 8; ++j) a[j] += __shfl_xor(a[j], msk);
                }
                if (ew == 0) {   // write-back into own row, slot-swizzled
                    bf16x8 o;
                    #pragma unroll
                    for (int j = 0; j < 8; ++j) o[j] = (short)bf16rne(a[j]);
                    int sl = f8 ^ (ld & 7);
                    *(bf16x8*)&csB[ld * 64 + sl * 8] = o;
                }
            } else if (ew == 0) {   // zero-fill invalid node rows
                bf16x8 z = {0,0,0,0,0,0,0,0};
                int sl = f8 ^ (ld & 7);
                *(bf16x8*)&csB[ld * 64 + sl * 8] = z;
            }
        }
    }
    __syncthreads();

    // ---- update: wave wv -> tile nodes [wv*16, wv*16+16) ----
    const int c = lane & 15, q = lane >> 4;
    float bias[4];
    #pragma unroll
    for (int nt = 0; nt < 4; ++nt) bias[nt] = b[nt * 16 + c];

    int ovnc = ovn; if (ovnc > OVL) ovnc = OVL;

    int wn0 = wv * 16;
    int nm = base + wn0 + c;
    int nmc = nm < N ? nm : N - 1;
    int dtot = cnt_l[wn0 + c];                 // TRUE degree
    float inv = 1.0f / fmaxf((float)dtot, 1.0f);

    bf16x8 a0 = *(const bf16x8*)&hbs[(size_t)nmc * DF + q * 8];
    bf16x8 a1 = *(const bf16x8*)&hbs[(size_t)nmc * DF + 32 + q * 8];
    bf16x8 a2, a3;
    #pragma unroll
    for (int kc = 0; kc < 2; ++kc) {
        int srow = wn0 + c;
        int sl = (kc * 4 + q) ^ (srow & 7);    // inverse of the write swizzle
        bf16x8 u = *(const bf16x8*)&csB[srow * 64 + sl * 8];
        float e[8];
        #pragma unroll
        for (int i = 0; i < 8; ++i) e[i] = b2f((unsigned short)u[i]);
        if (ovnc > 0) {
            for (int t2 = 0; t2 < ovnc; ++t2) {
                if (ovl[2 * t2] == wn0 + c) {  // deg>32 extras (counted in dtot)
                    bf16x8 hu = *(const bf16x8*)&hbs[(size_t)ovl[2 * t2 + 1] * DF + kc * 32 + q * 8];
                    #pragma unroll
                    for (int i = 0; i < 8; ++i) e[i] += b2f((unsigned short)hu[i]);
                }
            }
        }
        bf16x8 f;
        #pragma unroll
        for (int i = 0; i < 8; ++i) f[i] = (short)bf16rne(e[i] * inv);
        if (kc == 0) a2 = f; else a3 = f;
    }

    #define WF(nt, kt) (*(const bf16x8*)&Wl[((nt) * 16 + c) * WPAD + (kt) * 32 + q * 8])
    f32x4 acc0 = {bias[0], bias[0], bias[0], bias[0]};
    f32x4 acc1 = {bias[1], bias[1], bias[1], bias[1]};
    f32x4 acc2 = {bias[2], bias[2], bias[2], bias[2]};
    f32x4 acc3 = {bias[3], bias[3], bias[3], bias[3]};
    acc0 = __builtin_amdgcn_mfma_f32_16x16x32_bf16(a0, WF(0,0), acc0, 0, 0, 0);
    acc0 = __builtin_amdgcn_mfma_f32_16x16x32_bf16(a1, WF(0,1), acc0, 0, 0, 0);
    acc0 = __builtin_amdgcn_mfma_f32_16x16x32_bf16(a2, WF(0,2), acc0, 0, 0, 0);
    acc0 = __builtin_amdgcn_mfma_f32_16x16x32_bf16(a3, WF(0,3), acc0, 0, 0, 0);
    acc1 = __builtin_amdgcn_mfma_f32_16x16x32_bf16(a0, WF(1,0), acc1, 0, 0, 0);
    acc1 = __builtin_amdgcn_mfma_f32_16x16x32_bf16(a1, WF(1,1), acc1, 0, 0, 0);
    acc1 = __builtin_amdgcn_mfma_f32_16x16x32_bf16(a2, WF(1,2), acc1, 0, 0, 0);
    acc1 = __builtin_amdgcn_mfma_f32_16x16x32_bf16(a3, WF(1,3), acc1, 0, 0, 0);
    acc2 = __builtin_amdgcn_mfma_f32_16x16x32_bf16(a0, WF(2,0), acc2, 0, 0, 0);
    acc2 = __builtin_amdgcn_mfma_f32_16x16x32_bf16(a1, WF(2,1), acc2, 0, 0, 0);
    acc2 = __builtin_amdgcn_mfma_f32_16x16x32_bf16(a2, WF(2,2), acc2, 0, 0, 0);
    acc2 = __builtin_amdgcn_mfma_f32_16x16x32_bf16(a3, WF(2,3), acc2, 0, 0, 0);
    acc3 = __builtin_amdgcn_mfma_f32_16x16x32_bf16(a0, WF(3,0), acc3, 0, 0, 0);
    acc3 = __builtin_amdgcn_mfma_f32_16x16x32_bf16(a1, WF(3,1), acc3, 0, 0, 0);
    acc3 = __builtin_amdgcn_mfma_f32_16x16x32_bf16(a2, WF(3,2), acc3, 0, 0, 0);
    acc3 = __builtin_amdgcn_mfma_f32_16x16x32_bf16(a3, WF(3,3), acc3, 0, 0, 0);
    #undef WF

    float ss[4];
    #pragma unroll
    for (int r = 0; r < 4; ++r)
        ss[r] = acc0[r] * acc0[r] + acc1[r] * acc1[r]
              + acc2[r] * acc2[r] + acc3[r] * acc3[r];
    #pragma unroll
    for (int msk = 1; msk <= 8; msk <<= 1) {
        ss[0] += __shfl_xor(ss[0], msk);
        ss[1] += __shfl_xor(ss[1], msk);
        ss[2] += __shfl_xor(ss[2], msk);
        ss[3] += __shfl_xor(ss[3], msk);
    }
    #pragma unroll
    for (int r = 0; r < 4; ++r) {
        int nr = base + wn0 + q * 4 + r;
        int dr = __shfl(dtot, q * 4 + r);
        if (nr < N) {
            float rin = 1.0f / fmaxf(sqrtf(ss[r]), 1e-12f);
            const float* hp = &h[(size_t)nr * DF + c];
            float hv0 = hp[0], hv1 = hp[16], hv2 = hp[32], hv3 = hp[48];
            bool up = dr > 0;
            float o0 = hv0 + (up ? fmaxf(acc0[r] * rin, 0.f) : hv0);
            float o1 = hv1 + (up ? fmaxf(acc1[r] * rin, 0.f) : hv1);
            float o2 = hv2 + (up ? fmaxf(acc2[r] * rin, 0.f) : hv2);
            float o3 = hv3 + (up ? fmaxf(acc3[r] * rin, 0.f) : hv3);
            float* op = &out[(size_t)nr * DF + c];
            op[0] = o0; op[16] = o1; op[32] = o2; op[48] = o3;
        }
    }
}

extern "C" void kernel_launch(void* const* d_in, const int* in_sizes, int n_in,
                              void* d_out, int out_size, void* d_ws, size_t ws_size,
                              hipStream_t stream) {
    const float* h   = (const float*)d_in[0];
    const float* W   = (const float*)d_in[1];
    const float* b   = (const float*)d_in[2];
    const int*   src = (const int*)d_in[3];
    const int*   dst = (const int*)d_in[4];
    float* out = (float*)d_out;

    const int N = in_sizes[0] / DF;
    const int E = in_sizes[3];
    const int NBK = (N + 511) >> BSH;                  // 196
    int NCH = (E + 2047) / 2048;                       // ~782 bin blocks
    if (NCH > MAXCH) NCH = MAXCH;
    const int EPB = (E + NCH - 1) / NCH;               // ~2048 edges/block

    // workspace carve (16B-aligned); no pre-zeroing needed
    unsigned short* Wbs = (unsigned short*)d_ws;                       // 64*128
    unsigned short* hbs = Wbs + 64 * 128;                              // (N+1)*64
    unsigned* pairs = (unsigned*)(hbs + (((size_t)(N + 1) * DF + 15) & ~(size_t)15));
    int* bcnt = (int*)(pairs + (size_t)NBK * NCH * CAP);               // [NBK][NCH]
    int* bovn = bcnt + (((size_t)NBK * NCH + 15) & ~(size_t)15);       // NCH
    unsigned long long* ovfb =
        (unsigned long long*)(bovn + ((NCH + 15) & ~15));              // NCH*OCAP

    // K1: fused bf16 conversions + single-pass edge binning
    conv_bin<<<NCH, 512, 0, stream>>>(
        h, W, src, dst, hbs, Wbs, pairs, bcnt, ovfb, bovn, N, E, NBK, NCH, EPB);

    // K2: fused build + gather + MFMA update (782 blocks, 4/CU, no tail)
    gather_update<<<(N + WIN - 1) / WIN, 512, 0, stream>>>(
        pairs, bcnt, ovfb, bovn, hbs, Wbs, h, b, out, N, NBK, NCH);
}